// Round 26
// baseline (195.983 us; speedup 1.0000x reference)
//
#include <hip/hip_runtime.h>

#define D 128           // feature dim
#define CHUNK 8192      // edges per partition block
#define NCHUNK_MAX 256  // supports E <= 2M
#define BSH 7           // bucket shift: bucket = 128 nodes
#define BUCKET 128
#define NB_MAX 1024     // supports N <= 131072
#define STAGE_CAP 3072  // sort_agg LDS stage entries (max random bucket ~2.4K)
#define DEGB 512        // out-degree histogram role blocks

typedef __attribute__((ext_vector_type(8))) short bf16x8;
typedef __attribute__((ext_vector_type(4))) float f32x4;

// ---------------------------------------------------------------------------
// bf16 pack (RNE; low 16 bits = FIRST element)
// ---------------------------------------------------------------------------
__device__ __forceinline__ unsigned int pack_bf16(float a, float b) {
    unsigned int ua = __float_as_uint(a), ub = __float_as_uint(b);
    ua = (ua + 0x7fffu + ((ua >> 16) & 1u)) >> 16;
    ub = (ub + 0x7fffu + ((ub >> 16) & 1u)) >> 16;
    return (ub << 16) | (ua & 0xffffu);
}

// inclusive wave-scan (64 lanes) of v; returns inclusive prefix for this lane
__device__ __forceinline__ int wave_iscan(int v, int lane) {
    #pragma unroll
    for (int off = 1; off < 64; off <<= 1) {
        int x = __shfl_up(v, off);
        if (lane >= off) v += x;
    }
    return v;
}

// ---------------------------------------------------------------------------
// conv_w: Wt_bf16[col][k] = bf16(W[k][col])  (128x128 = 16384 shorts = 32 KB)
// ---------------------------------------------------------------------------
__global__ __launch_bounds__(256) void conv_w(const float* __restrict__ W,
                                              unsigned short* __restrict__ Wtb) {
    int i = blockIdx.x * 256 + threadIdx.x;   // 16384 total
    int col = i >> 7, k = i & 127;
    unsigned int u = __float_as_uint(W[k * D + col]);
    u = (u + 0x7fffu + ((u >> 16) & 1u)) >> 16;
    Wtb[i] = (unsigned short)u;
}

// ---------------------------------------------------------------------------
// Phase 1 (fused, 256-thread blocks, 3 roles):
//  [0, nchunk)            partition 8192 edges by 128-node dst bucket
//  [nchunk, nchunk+DEGB)  out-degree histogram (int4, fire-and-forget)
//  [nchunk+DEGB, ...)     hw = bf16(h @ W) via MFMA 16x16x32, 64-row tile
// ---------------------------------------------------------------------------
struct Phase1Smem {
    struct {
        int hist[NB_MAX];            // counts -> offsets -> cursors
        unsigned int stage[CHUNK];
    } p;                              // 36 KB (partition role only)
};

__global__ __launch_bounds__(256) void phase1(const float* __restrict__ h,
                                              const unsigned short* __restrict__ Wtb,
                                              const int* __restrict__ src,
                                              const int* __restrict__ dst,
                                              unsigned int* __restrict__ pairs,
                                              int* __restrict__ cnt_g,
                                              int* __restrict__ loff_g,
                                              int* __restrict__ outdeg,
                                              unsigned int* __restrict__ hw,
                                              int E, int nb, int nchunk, int N) {
    __shared__ Phase1Smem sm;
    __shared__ int redw[4];
    const int t   = threadIdx.x;
    const int bid = (int)blockIdx.x;

    if (bid < nchunk) {
        // ---------------- partition role (priority-boosted) ----------------
        __builtin_amdgcn_s_setprio(1);
        const int c  = bid;
        const int e0 = c * CHUNK;
        const int n  = min(CHUNK, E - e0);

        for (int i = t; i < nb; i += 256) sm.p.hist[i] = 0;
        __syncthreads();

        // pass 1: bucket histogram
        for (int i = t; i < n; i += 256) {
            int d = dst[e0 + i];
            atomicAdd(&sm.p.hist[d >> BSH], 1);
        }
        __syncthreads();

        // export counts
        for (int i = t; i < nb; i += 256) cnt_g[(size_t)c * nb + i] = sm.p.hist[i];
        __syncthreads();

        // PARALLEL exclusive scan of hist[0..nb) in place (4 elems/thread)
        {
            const int lane = t & 63;
            const int w    = t >> 6;
            const int i0   = t * 4;
            int v0 = (i0 + 0 < nb) ? sm.p.hist[i0 + 0] : 0;
            int v1 = (i0 + 1 < nb) ? sm.p.hist[i0 + 1] : 0;
            int v2 = (i0 + 2 < nb) ? sm.p.hist[i0 + 2] : 0;
            int v3 = (i0 + 3 < nb) ? sm.p.hist[i0 + 3] : 0;
            int s   = v0 + v1 + v2 + v3;
            int inc = wave_iscan(s, lane);
            if (lane == 63) redw[w] = inc;
            __syncthreads();
            int wpre = 0;
            #pragma unroll
            for (int q = 0; q < 4; ++q) wpre += (q < w) ? redw[q] : 0;
            int excl = wpre + inc - s;
            if (i0 + 0 < nb) sm.p.hist[i0 + 0] = excl;  excl += v0;
            if (i0 + 1 < nb) sm.p.hist[i0 + 1] = excl;  excl += v1;
            if (i0 + 2 < nb) sm.p.hist[i0 + 2] = excl;  excl += v2;
            if (i0 + 3 < nb) sm.p.hist[i0 + 3] = excl;
        }
        __syncthreads();

        // export offsets (hist now doubles as the pass-2 cursor array)
        for (int i = t; i < nb; i += 256) loff_g[(size_t)c * nb + i] = sm.p.hist[i];
        __syncthreads();

        // pass 2: scatter into LDS stage (no global atomics in this loop)
        for (int i = t; i < n; i += 256) {
            int d = dst[e0 + i];
            int s = src[e0 + i];
            int slot = atomicAdd(&sm.p.hist[d >> BSH], 1);
            sm.p.stage[slot] = ((unsigned int)(d & (BUCKET - 1)) << 24) | (unsigned int)s;
        }
        __syncthreads();

        // pass 3: dense streamout (uint4)
        {
            const int n4 = n >> 2;
            uint4* pout = reinterpret_cast<uint4*>(pairs + e0);
            const uint4* pin = reinterpret_cast<const uint4*>(sm.p.stage);
            for (int i = t; i < n4; i += 256) pout[i] = pin[i];
            for (int i = (n4 << 2) + t; i < n; i += 256) pairs[e0 + i] = sm.p.stage[i];
        }
        __builtin_amdgcn_s_setprio(0);
    } else if (bid < nchunk + DEGB) {
        // ---------------- out-degree role (int4, fire-and-forget) ----------
        const int E4 = E >> 2;
        const int4* src4 = reinterpret_cast<const int4*>(src);
        int i = (bid - nchunk) * 256 + t;
        const int stride = DEGB * 256;
        for (; i < E4; i += stride) {
            int4 s4 = src4[i];
            atomicAdd(&outdeg[s4.x], 1);
            atomicAdd(&outdeg[s4.y], 1);
            atomicAdd(&outdeg[s4.z], 1);
            atomicAdd(&outdeg[s4.w], 1);
        }
        for (i = (E4 << 2) + (bid - nchunk) * 256 + t; i < E; i += stride)
            atomicAdd(&outdeg[src[i]], 1);
    } else {
        // ---------------- GEMM role (MFMA, 64-row tile, no LDS) ------------
        const int r0 = (bid - nchunk - DEGB) * 64;
        const int w  = t >> 6;          // wave 0..3 -> rows w*16..w*16+15
        const int l  = t & 63;
        const int hr = l & 15;          // lane's h-row within the 16
        const int cg = l >> 4;          // k-group / col-group (0..3)

        const int gr  = r0 + w * 16 + hr;
        const int grc = (gr < N) ? gr : (N - 1);   // clamp for safe loads

        f32x4 acc[8];
        #pragma unroll
        for (int ct = 0; ct < 8; ++ct) acc[ct] = (f32x4){0.f, 0.f, 0.f, 0.f};

        #pragma unroll
        for (int kg = 0; kg < 4; ++kg) {
            const float* hp = h + (size_t)grc * D + kg * 32 + cg * 8;
            float4 h0 = reinterpret_cast<const float4*>(hp)[0];
            float4 h1 = reinterpret_cast<const float4*>(hp)[1];
            unsigned int hu[4] = { pack_bf16(h0.x, h0.y), pack_bf16(h0.z, h0.w),
                                   pack_bf16(h1.x, h1.y), pack_bf16(h1.z, h1.w) };
            bf16x8 hf = *reinterpret_cast<bf16x8*>(hu);

            #pragma unroll
            for (int ct = 0; ct < 8; ++ct) {
                bf16x8 wf = *reinterpret_cast<const bf16x8*>(
                    Wtb + ((size_t)(ct * 16 + hr) * D + kg * 32 + cg * 8));
                acc[ct] = __builtin_amdgcn_mfma_f32_16x16x32_bf16(wf, hf, acc[ct], 0, 0, 0);
            }
        }

        if (gr < N) {
            #pragma unroll
            for (int ct = 0; ct < 8; ++ct) {
                int cpb = ct * 8 + cg * 2;
                hw[(size_t)gr * 64 + cpb]     = pack_bf16(acc[ct][0], acc[ct][1]);
                hw[(size_t)gr * 64 + cpb + 1] = pack_bf16(acc[ct][2], acc[ct][3]);
            }
        }
    }
}

// ---------------------------------------------------------------------------
// sort_agg: fused {per-bucket counting sort -> LDS} + {gather hw rows, fused
// deg/bias epilogue}. One 512-thread block (8 waves) per 128-node bucket.
// ---------------------------------------------------------------------------
__global__ __launch_bounds__(512) void sort_agg(const unsigned int* __restrict__ pairs,
                                                const int* __restrict__ cnt_g,
                                                const int* __restrict__ loff_g,
                                                const unsigned int* __restrict__ hw,
                                                const int* __restrict__ outdeg,
                                                const float* __restrict__ bias,
                                                float* __restrict__ out,
                                                int nb, int nchunk, int N) {
    __shared__ int sec_base[NCHUNK_MAX + 1];
    __shared__ int sec_lo[NCHUNK_MAX];
    __shared__ int dstart[BUCKET + 1];
    __shared__ int dcur[BUCKET];
    __shared__ int redw[8];
    __shared__ unsigned int stage[STAGE_CAP];

    const int t    = threadIdx.x;
    const int b    = blockIdx.x;
    const int lane = t & 63;
    const int w    = t >> 6;

    for (int c = t; c < nchunk; c += 512) {
        sec_base[c] = cnt_g[(size_t)c * nb + b];
        sec_lo[c]   = loff_g[(size_t)c * nb + b];
    }
    if (t < BUCKET) dstart[t] = 0;
    __syncthreads();

    // PARALLEL exclusive scan of sec_base[0..nchunk) (1 elem/thread)
    {
        int v   = (t < nchunk) ? sec_base[t] : 0;
        int inc = wave_iscan(v, lane);
        if (lane == 63) redw[w] = inc;
        __syncthreads();
        int wpre = 0;
        #pragma unroll
        for (int q = 0; q < 8; ++q) wpre += (q < w) ? redw[q] : 0;
        int excl = wpre + inc - v;
        __syncthreads();
        if (t < nchunk) sec_base[t] = excl;
        if (t == nchunk - 1) sec_base[nchunk] = excl + v;
    }
    __syncthreads();

    const int total = sec_base[nchunk];

    // pass 1: local-dst histogram (binary search section)
    for (int j = t; j < total; j += 512) {
        int lo = 0, hi = nchunk - 1;
        while (lo < hi) { int mid = (lo + hi + 1) >> 1; if (sec_base[mid] <= j) lo = mid; else hi = mid - 1; }
        unsigned int p = pairs[(size_t)lo * CHUNK + sec_lo[lo] + (j - sec_base[lo])];
        atomicAdd(&dstart[p >> 24], 1);
    }
    __syncthreads();

    // PARALLEL exclusive scan of dstart[0..BUCKET)
    {
        int v   = (t < BUCKET) ? dstart[t] : 0;
        int inc = wave_iscan(v, lane);
        if (lane == 63) redw[w] = inc;
        __syncthreads();
        int wpre = 0;
        #pragma unroll
        for (int q = 0; q < 8; ++q) wpre += (q < w) ? redw[q] : 0;
        int excl = wpre + inc - v;
        __syncthreads();
        if (t < BUCKET) { dstart[t] = excl; dcur[t] = excl; }
        if (t == BUCKET - 1) dstart[BUCKET] = excl + v;
    }
    __syncthreads();

    const float2 bb = reinterpret_cast<const float2*>(bias)[lane];

    if (total <= STAGE_CAP) {
        // pass 2: scatter src into LDS stage ordered by local dst
        for (int j = t; j < total; j += 512) {
            int lo = 0, hi = nchunk - 1;
            while (lo < hi) { int mid = (lo + hi + 1) >> 1; if (sec_base[mid] <= j) lo = mid; else hi = mid - 1; }
            unsigned int p = pairs[(size_t)lo * CHUNK + sec_lo[lo] + (j - sec_base[lo])];
            int slot = atomicAdd(&dcur[p >> 24], 1);
            stage[slot] = p & 0xFFFFFFu;
        }
        __syncthreads();

        // gather + epilogue: wave per local node, round-robin, ILP-8
        for (int r = w; r < BUCKET; r += 8) {
            const int node = (b << BSH) + r;
            if (node >= N) break;
            const int e0 = dstart[r], e1 = dstart[r + 1];
            float ax = 0.f, ay = 0.f;
            int e = e0;
            for (; e + 8 <= e1; e += 8) {
                int sx[8];
                #pragma unroll
                for (int q = 0; q < 8; ++q) sx[q] = (int)stage[e + q];
                unsigned int u[8];
                #pragma unroll
                for (int q = 0; q < 8; ++q) u[q] = hw[(size_t)sx[q] * 64 + lane];
                #pragma unroll
                for (int q = 0; q < 8; ++q) {
                    ax += __uint_as_float(u[q] << 16);
                    ay += __uint_as_float(u[q] & 0xffff0000u);
                }
            }
            for (; e + 4 <= e1; e += 4) {
                int s0 = (int)stage[e],     s1 = (int)stage[e + 1];
                int s2 = (int)stage[e + 2], s3 = (int)stage[e + 3];
                unsigned int u0 = hw[(size_t)s0 * 64 + lane];
                unsigned int u1 = hw[(size_t)s1 * 64 + lane];
                unsigned int u2 = hw[(size_t)s2 * 64 + lane];
                unsigned int u3 = hw[(size_t)s3 * 64 + lane];
                ax += __uint_as_float(u0 << 16) + __uint_as_float(u1 << 16)
                    + __uint_as_float(u2 << 16) + __uint_as_float(u3 << 16);
                ay += __uint_as_float(u0 & 0xffff0000u) + __uint_as_float(u1 & 0xffff0000u)
                    + __uint_as_float(u2 & 0xffff0000u) + __uint_as_float(u3 & 0xffff0000u);
            }
            for (; e < e1; ++e) {
                unsigned int u = hw[(size_t)stage[e] * 64 + lane];
                ax += __uint_as_float(u << 16);
                ay += __uint_as_float(u & 0xffff0000u);
            }
            float sc = 1.0f / (float)outdeg[node];
            float2 o;
            o.x = ax * sc + bb.x;
            o.y = ay * sc + bb.y;
            reinterpret_cast<float2*>(out + (size_t)node * D)[lane] = o;
        }
    } else {
        // slow path (pathological skew only): wave per node, full bucket scan
        for (int r = w; r < BUCKET; r += 8) {
            const int node = (b << BSH) + r;
            if (node >= N) break;
            float ax = 0.f, ay = 0.f;
            for (int c = 0; c < nchunk; ++c) {
                const int cb = sec_base[c], ce = sec_base[c + 1];
                const size_t pb = (size_t)c * CHUNK + sec_lo[c];
                for (int j = cb; j < ce; ++j) {
                    unsigned int p = pairs[pb + (j - cb)];
                    if ((int)(p >> 24) == r) {
                        unsigned int u = hw[(size_t)(p & 0xFFFFFFu) * 64 + lane];
                        ax += __uint_as_float(u << 16);
                        ay += __uint_as_float(u & 0xffff0000u);
                    }
                }
            }
            float sc = 1.0f / (float)outdeg[node];
            float2 o;
            o.x = ax * sc + bb.x;
            o.y = ay * sc + bb.y;
            reinterpret_cast<float2*>(out + (size_t)node * D)[lane] = o;
        }
    }
}

// ---------------------------------------------------------------------------
// Tier-3 fallback: atomic scatter path (shape-independent)
// ---------------------------------------------------------------------------
__global__ void deg_kernel(const int* __restrict__ src, int* __restrict__ deg, int E) {
    int i = blockIdx.x * blockDim.x + threadIdx.x;
    int stride = gridDim.x * blockDim.x;
    for (; i < E; i += stride) atomicAdd(&deg[src[i]], 1);
}

__global__ void scatter_kernel(const float* __restrict__ h,
                               const int* __restrict__ src,
                               const int* __restrict__ dst,
                               float* __restrict__ agg, int E) {
    int wave   = (int)((blockIdx.x * blockDim.x + threadIdx.x) >> 6);
    int lane   = threadIdx.x & 63;
    int nwaves = (int)((gridDim.x * blockDim.x) >> 6);
    for (int e = wave; e < E; e += nwaves) {
        int s = src[e];
        int d = dst[e];
        const float2 v = reinterpret_cast<const float2*>(h + (size_t)s * D)[lane];
        float* arow = agg + (size_t)d * D + lane * 2;
        atomicAdd(arow + 0, v.x);
        atomicAdd(arow + 1, v.y);
    }
}

__global__ __launch_bounds__(256) void gemm_finish(float* __restrict__ out,
                                                   const float* __restrict__ Wm,
                                                   const float* __restrict__ bias,
                                                   const int* __restrict__ deg,
                                                   int N) {
    __shared__ __align__(16) float tile[64][D];
    const int r0 = blockIdx.x * 64;
    const int t  = threadIdx.x;

    #pragma unroll
    for (int i = 0; i < 8; ++i) {
        int flat4 = i * 256 + t;
        int r     = flat4 >> 5;
        int c4    = flat4 & 31;
        int gr    = r0 + r;
        float4 v  = make_float4(0.f, 0.f, 0.f, 0.f);
        if (gr < N) v = reinterpret_cast<const float4*>(out + (size_t)gr * D)[c4];
        reinterpret_cast<float4*>(&tile[r][c4 * 4])[0] = v;
    }
    __syncthreads();

    const int wsel = t >> 6;
    const int j0   = (t & 63) * 2;

    float acc[16][2];
    #pragma unroll
    for (int r = 0; r < 16; ++r) { acc[r][0] = 0.f; acc[r][1] = 0.f; }

    for (int k = 0; k < D; k += 4) {
        float2 w[4];
        #pragma unroll
        for (int kk = 0; kk < 4; ++kk)
            w[kk] = reinterpret_cast<const float2*>(Wm + (size_t)(k + kk) * D + j0)[0];
        #pragma unroll
        for (int r = 0; r < 16; ++r) {
            float4 a = reinterpret_cast<const float4*>(&tile[wsel * 16 + r][k])[0];
            acc[r][0] += a.x * w[0].x + a.y * w[1].x + a.z * w[2].x + a.w * w[3].x;
            acc[r][1] += a.x * w[0].y + a.y * w[1].y + a.z * w[2].y + a.w * w[3].y;
        }
    }

    const float2 bb = reinterpret_cast<const float2*>(bias + j0)[0];
    #pragma unroll
    for (int r = 0; r < 16; ++r) {
        int gr = r0 + wsel * 16 + r;
        if (gr < N) {
            float sc = 1.0f / (float)deg[gr];
            float2 o;
            o.x = acc[r][0] * sc + bb.x;
            o.y = acc[r][1] * sc + bb.y;
            reinterpret_cast<float2*>(out + (size_t)gr * D + j0)[0] = o;
        }
    }
}

// ---------------------------------------------------------------------------
extern "C" void kernel_launch(void* const* d_in, const int* in_sizes, int n_in,
                              void* d_out, int out_size, void* d_ws, size_t ws_size,
                              hipStream_t stream) {
    const float* h   = (const float*)d_in[0];
    const float* Wm  = (const float*)d_in[1];
    const float* bia = (const float*)d_in[2];
    const int*   src = (const int*)d_in[3];
    const int*   dst = (const int*)d_in[4];
    float*       out = (float*)d_out;

    const int N = in_sizes[0] / D;   // 100000
    const int E = in_sizes[3];       // 1700000

    const int nb      = (N + BUCKET - 1) >> BSH;
    const int nchunk  = (E + CHUNK - 1) / CHUNK;
    const int gblocks = (N + 63) / 64;

    // ws (ints): outdeg[N] | Wtb[16384 shorts = 8192 ints] | cnt[nchunk*nb] |
    //            loff[nchunk*nb] | pairs[nchunk*CHUNK] | hw[N*64]
    size_t tier1_ints = (size_t)N + 8192 + (size_t)2 * nchunk * nb
                      + (size_t)nchunk * CHUNK + (size_t)N * 64;

    bool shape_ok = (N < (1 << 24)) && nb <= NB_MAX && nchunk <= NCHUNK_MAX;

    if (shape_ok && ws_size >= tier1_ints * sizeof(int)) {
        int* outdeg = (int*)d_ws;
        unsigned short* Wtb = (unsigned short*)(outdeg + N);
        int* cnt_g  = (int*)Wtb + 8192;   // 8192 ints = 16384 shorts past Wtb
        int* loff_g = cnt_g + (size_t)nchunk * nb;
        unsigned int* pairs = (unsigned int*)(loff_g + (size_t)nchunk * nb);
        unsigned int* hw = pairs + (size_t)nchunk * CHUNK;

        hipMemsetAsync(outdeg, 0, (size_t)N * sizeof(int), stream);

        conv_w<<<64, 256, 0, stream>>>(Wm, Wtb);

        phase1<<<nchunk + DEGB + gblocks, 256, 0, stream>>>(h, Wtb, src, dst, pairs,
                                                            cnt_g, loff_g, outdeg,
                                                            hw, E, nb, nchunk, N);

        sort_agg<<<nb, 512, 0, stream>>>(pairs, cnt_g, loff_g, hw,
                                         outdeg, bia, out, nb, nchunk, N);
    } else {
        // fallback: atomic scatter path
        int* deg = (int*)d_ws;
        hipMemsetAsync(out, 0, (size_t)out_size * sizeof(float), stream);
        hipMemsetAsync(deg, 0, (size_t)N * sizeof(int), stream);
        deg_kernel<<<2048, 256, 0, stream>>>(src, deg, E);
        scatter_kernel<<<8192, 256, 0, stream>>>(h, src, dst, out, E);
        gemm_finish<<<(N + 63) / 64, 256, 0, stream>>>(out, Wm, bia, deg, N);
    }
}

// Round 27
// 180.992 us; speedup vs baseline: 1.0828x; 1.0828x over previous
//
#include <hip/hip_runtime.h>

#define D 128           // feature dim
#define CHUNK 8192      // edges per partition block
#define NCHUNK_MAX 256  // supports E <= 2M
#define BSH 7           // bucket shift: bucket = 128 nodes
#define BUCKET 128
#define NB_MAX 1024     // supports N <= 131072
#define STAGE_CAP 3072  // sort_agg LDS stage entries (max random bucket ~2.4K)
#define DEGB 256        // out-degree histogram role blocks

typedef __attribute__((ext_vector_type(8))) short bf16x8;
typedef __attribute__((ext_vector_type(4))) float f32x4;

// ---------------------------------------------------------------------------
// bf16 pack (RNE; low 16 bits = FIRST element)
// ---------------------------------------------------------------------------
__device__ __forceinline__ unsigned int pack_bf16(float a, float b) {
    unsigned int ua = __float_as_uint(a), ub = __float_as_uint(b);
    ua = (ua + 0x7fffu + ((ua >> 16) & 1u)) >> 16;
    ub = (ub + 0x7fffu + ((ub >> 16) & 1u)) >> 16;
    return (ub << 16) | (ua & 0xffffu);
}

// inclusive wave-scan (64 lanes) of v; returns inclusive prefix for this lane
__device__ __forceinline__ int wave_iscan(int v, int lane) {
    #pragma unroll
    for (int off = 1; off < 64; off <<= 1) {
        int x = __shfl_up(v, off);
        if (lane >= off) v += x;
    }
    return v;
}

// ---------------------------------------------------------------------------
// conv_w: Wt_bf16[col][k] = bf16(W[k][col])  (128x128 = 16384 shorts = 32 KB)
// ---------------------------------------------------------------------------
__global__ __launch_bounds__(256) void conv_w(const float* __restrict__ W,
                                              unsigned short* __restrict__ Wtb) {
    int i = blockIdx.x * 256 + threadIdx.x;   // 16384 total
    int col = i >> 7, k = i & 127;
    unsigned int u = __float_as_uint(W[k * D + col]);
    u = (u + 0x7fffu + ((u >> 16) & 1u)) >> 16;
    Wtb[i] = (unsigned short)u;
}

// ---------------------------------------------------------------------------
// Phase 1 (fused, 256-thread blocks, 3 roles):
//  [0, nchunk)            partition 8192 edges by 128-node dst bucket
//  [nchunk, nchunk+DEGB)  out-degree histogram (grid-stride on idle CUs)
//  [nchunk+DEGB, ...)     hw = bf16(h @ W) via MFMA 16x16x32, 64-row tile
// ---------------------------------------------------------------------------
struct Phase1Smem {
    struct {
        int hist[NB_MAX];            // counts -> offsets -> cursors
        unsigned int stage[CHUNK];
    } p;                              // 36 KB (partition role only)
};

__global__ __launch_bounds__(256) void phase1(const float* __restrict__ h,
                                              const unsigned short* __restrict__ Wtb,
                                              const int* __restrict__ src,
                                              const int* __restrict__ dst,
                                              unsigned int* __restrict__ pairs,
                                              int* __restrict__ cnt_g,
                                              int* __restrict__ loff_g,
                                              int* __restrict__ outdeg,
                                              unsigned int* __restrict__ hw,
                                              int E, int nb, int nchunk, int N) {
    __shared__ Phase1Smem sm;
    __shared__ int redw[4];
    const int t   = threadIdx.x;
    const int bid = (int)blockIdx.x;

    if (bid < nchunk) {
        // ---------------- partition role (priority-boosted) ----------------
        __builtin_amdgcn_s_setprio(1);
        const int c  = bid;
        const int e0 = c * CHUNK;
        const int n  = min(CHUNK, E - e0);

        for (int i = t; i < nb; i += 256) sm.p.hist[i] = 0;
        __syncthreads();

        // pass 1: bucket histogram
        for (int i = t; i < n; i += 256) {
            int d = dst[e0 + i];
            atomicAdd(&sm.p.hist[d >> BSH], 1);
        }
        __syncthreads();

        // export counts
        for (int i = t; i < nb; i += 256) cnt_g[(size_t)c * nb + i] = sm.p.hist[i];
        __syncthreads();

        // PARALLEL exclusive scan of hist[0..nb) in place (4 elems/thread)
        {
            const int lane = t & 63;
            const int w    = t >> 6;
            const int i0   = t * 4;
            int v0 = (i0 + 0 < nb) ? sm.p.hist[i0 + 0] : 0;
            int v1 = (i0 + 1 < nb) ? sm.p.hist[i0 + 1] : 0;
            int v2 = (i0 + 2 < nb) ? sm.p.hist[i0 + 2] : 0;
            int v3 = (i0 + 3 < nb) ? sm.p.hist[i0 + 3] : 0;
            int s   = v0 + v1 + v2 + v3;
            int inc = wave_iscan(s, lane);
            if (lane == 63) redw[w] = inc;
            __syncthreads();
            int wpre = 0;
            #pragma unroll
            for (int q = 0; q < 4; ++q) wpre += (q < w) ? redw[q] : 0;
            int excl = wpre + inc - s;
            if (i0 + 0 < nb) sm.p.hist[i0 + 0] = excl;  excl += v0;
            if (i0 + 1 < nb) sm.p.hist[i0 + 1] = excl;  excl += v1;
            if (i0 + 2 < nb) sm.p.hist[i0 + 2] = excl;  excl += v2;
            if (i0 + 3 < nb) sm.p.hist[i0 + 3] = excl;
        }
        __syncthreads();

        // export offsets (hist now doubles as the pass-2 cursor array)
        for (int i = t; i < nb; i += 256) loff_g[(size_t)c * nb + i] = sm.p.hist[i];
        __syncthreads();

        // pass 2: scatter into LDS stage (no global atomics in this loop)
        for (int i = t; i < n; i += 256) {
            int d = dst[e0 + i];
            int s = src[e0 + i];
            int slot = atomicAdd(&sm.p.hist[d >> BSH], 1);
            sm.p.stage[slot] = ((unsigned int)(d & (BUCKET - 1)) << 24) | (unsigned int)s;
        }
        __syncthreads();

        // pass 3: dense streamout
        for (int i = t; i < n; i += 256) pairs[e0 + i] = sm.p.stage[i];
        __builtin_amdgcn_s_setprio(0);
    } else if (bid < nchunk + DEGB) {
        // ---------------- out-degree role (grid-stride on idle CUs) --------
        int i = (bid - nchunk) * 256 + t;
        const int stride = DEGB * 256;
        for (; i < E; i += stride) atomicAdd(&outdeg[src[i]], 1);
    } else {
        // ---------------- GEMM role (MFMA, 64-row tile, no LDS) ------------
        const int r0 = (bid - nchunk - DEGB) * 64;
        const int w  = t >> 6;          // wave 0..3 -> rows w*16..w*16+15
        const int l  = t & 63;
        const int hr = l & 15;          // lane's h-row within the 16
        const int cg = l >> 4;          // k-group / col-group (0..3)

        const int gr  = r0 + w * 16 + hr;
        const int grc = (gr < N) ? gr : (N - 1);   // clamp for safe loads

        f32x4 acc[8];
        #pragma unroll
        for (int ct = 0; ct < 8; ++ct) acc[ct] = (f32x4){0.f, 0.f, 0.f, 0.f};

        #pragma unroll
        for (int kg = 0; kg < 4; ++kg) {
            const float* hp = h + (size_t)grc * D + kg * 32 + cg * 8;
            float4 h0 = reinterpret_cast<const float4*>(hp)[0];
            float4 h1 = reinterpret_cast<const float4*>(hp)[1];
            unsigned int hu[4] = { pack_bf16(h0.x, h0.y), pack_bf16(h0.z, h0.w),
                                   pack_bf16(h1.x, h1.y), pack_bf16(h1.z, h1.w) };
            bf16x8 hf = *reinterpret_cast<bf16x8*>(hu);

            #pragma unroll
            for (int ct = 0; ct < 8; ++ct) {
                bf16x8 wf = *reinterpret_cast<const bf16x8*>(
                    Wtb + ((size_t)(ct * 16 + hr) * D + kg * 32 + cg * 8));
                acc[ct] = __builtin_amdgcn_mfma_f32_16x16x32_bf16(wf, hf, acc[ct], 0, 0, 0);
            }
        }

        if (gr < N) {
            #pragma unroll
            for (int ct = 0; ct < 8; ++ct) {
                int cpb = ct * 8 + cg * 2;
                hw[(size_t)gr * 64 + cpb]     = pack_bf16(acc[ct][0], acc[ct][1]);
                hw[(size_t)gr * 64 + cpb + 1] = pack_bf16(acc[ct][2], acc[ct][3]);
            }
        }
    }
}

// ---------------------------------------------------------------------------
// sort_agg: fused {per-bucket counting sort -> LDS} + {gather hw rows, fused
// deg/bias epilogue}. One 512-thread block (8 waves) per 128-node bucket.
// ---------------------------------------------------------------------------
__global__ __launch_bounds__(512) void sort_agg(const unsigned int* __restrict__ pairs,
                                                const int* __restrict__ cnt_g,
                                                const int* __restrict__ loff_g,
                                                const unsigned int* __restrict__ hw,
                                                const int* __restrict__ outdeg,
                                                const float* __restrict__ bias,
                                                float* __restrict__ out,
                                                int nb, int nchunk, int N) {
    __shared__ int sec_base[NCHUNK_MAX + 1];
    __shared__ int sec_lo[NCHUNK_MAX];
    __shared__ int dstart[BUCKET + 1];
    __shared__ int dcur[BUCKET];
    __shared__ int redw[8];
    __shared__ unsigned int stage[STAGE_CAP];

    const int t    = threadIdx.x;
    const int b    = blockIdx.x;
    const int lane = t & 63;
    const int w    = t >> 6;

    for (int c = t; c < nchunk; c += 512) {
        sec_base[c] = cnt_g[(size_t)c * nb + b];
        sec_lo[c]   = loff_g[(size_t)c * nb + b];
    }
    if (t < BUCKET) dstart[t] = 0;
    __syncthreads();

    // PARALLEL exclusive scan of sec_base[0..nchunk) (1 elem/thread)
    {
        int v   = (t < nchunk) ? sec_base[t] : 0;
        int inc = wave_iscan(v, lane);
        if (lane == 63) redw[w] = inc;
        __syncthreads();
        int wpre = 0;
        #pragma unroll
        for (int q = 0; q < 8; ++q) wpre += (q < w) ? redw[q] : 0;
        int excl = wpre + inc - v;
        __syncthreads();
        if (t < nchunk) sec_base[t] = excl;
        if (t == nchunk - 1) sec_base[nchunk] = excl + v;
    }
    __syncthreads();

    const int total = sec_base[nchunk];

    // pass 1: local-dst histogram (binary search section)
    for (int j = t; j < total; j += 512) {
        int lo = 0, hi = nchunk - 1;
        while (lo < hi) { int mid = (lo + hi + 1) >> 1; if (sec_base[mid] <= j) lo = mid; else hi = mid - 1; }
        unsigned int p = pairs[(size_t)lo * CHUNK + sec_lo[lo] + (j - sec_base[lo])];
        atomicAdd(&dstart[p >> 24], 1);
    }
    __syncthreads();

    // PARALLEL exclusive scan of dstart[0..BUCKET)
    {
        int v   = (t < BUCKET) ? dstart[t] : 0;
        int inc = wave_iscan(v, lane);
        if (lane == 63) redw[w] = inc;
        __syncthreads();
        int wpre = 0;
        #pragma unroll
        for (int q = 0; q < 8; ++q) wpre += (q < w) ? redw[q] : 0;
        int excl = wpre + inc - v;
        __syncthreads();
        if (t < BUCKET) { dstart[t] = excl; dcur[t] = excl; }
        if (t == BUCKET - 1) dstart[BUCKET] = excl + v;
    }
    __syncthreads();

    const float2 bb = reinterpret_cast<const float2*>(bias)[lane];

    if (total <= STAGE_CAP) {
        // pass 2: scatter src into LDS stage ordered by local dst
        for (int j = t; j < total; j += 512) {
            int lo = 0, hi = nchunk - 1;
            while (lo < hi) { int mid = (lo + hi + 1) >> 1; if (sec_base[mid] <= j) lo = mid; else hi = mid - 1; }
            unsigned int p = pairs[(size_t)lo * CHUNK + sec_lo[lo] + (j - sec_base[lo])];
            int slot = atomicAdd(&dcur[p >> 24], 1);
            stage[slot] = p & 0xFFFFFFu;
        }
        __syncthreads();

        // gather + epilogue: wave per local node, round-robin, ILP-8
        for (int r = w; r < BUCKET; r += 8) {
            const int node = (b << BSH) + r;
            if (node >= N) break;
            const int e0 = dstart[r], e1 = dstart[r + 1];
            float ax = 0.f, ay = 0.f;
            int e = e0;
            for (; e + 8 <= e1; e += 8) {
                int sx[8];
                #pragma unroll
                for (int q = 0; q < 8; ++q) sx[q] = (int)stage[e + q];
                unsigned int u[8];
                #pragma unroll
                for (int q = 0; q < 8; ++q) u[q] = hw[(size_t)sx[q] * 64 + lane];
                #pragma unroll
                for (int q = 0; q < 8; ++q) {
                    ax += __uint_as_float(u[q] << 16);
                    ay += __uint_as_float(u[q] & 0xffff0000u);
                }
            }
            for (; e + 4 <= e1; e += 4) {
                int s0 = (int)stage[e],     s1 = (int)stage[e + 1];
                int s2 = (int)stage[e + 2], s3 = (int)stage[e + 3];
                unsigned int u0 = hw[(size_t)s0 * 64 + lane];
                unsigned int u1 = hw[(size_t)s1 * 64 + lane];
                unsigned int u2 = hw[(size_t)s2 * 64 + lane];
                unsigned int u3 = hw[(size_t)s3 * 64 + lane];
                ax += __uint_as_float(u0 << 16) + __uint_as_float(u1 << 16)
                    + __uint_as_float(u2 << 16) + __uint_as_float(u3 << 16);
                ay += __uint_as_float(u0 & 0xffff0000u) + __uint_as_float(u1 & 0xffff0000u)
                    + __uint_as_float(u2 & 0xffff0000u) + __uint_as_float(u3 & 0xffff0000u);
            }
            for (; e < e1; ++e) {
                unsigned int u = hw[(size_t)stage[e] * 64 + lane];
                ax += __uint_as_float(u << 16);
                ay += __uint_as_float(u & 0xffff0000u);
            }
            float sc = 1.0f / (float)outdeg[node];
            float2 o;
            o.x = ax * sc + bb.x;
            o.y = ay * sc + bb.y;
            reinterpret_cast<float2*>(out + (size_t)node * D)[lane] = o;
        }
    } else {
        // slow path (pathological skew only): wave per node, full bucket scan
        for (int r = w; r < BUCKET; r += 8) {
            const int node = (b << BSH) + r;
            if (node >= N) break;
            float ax = 0.f, ay = 0.f;
            for (int c = 0; c < nchunk; ++c) {
                const int cb = sec_base[c], ce = sec_base[c + 1];
                const size_t pb = (size_t)c * CHUNK + sec_lo[c];
                for (int j = cb; j < ce; ++j) {
                    unsigned int p = pairs[pb + (j - cb)];
                    if ((int)(p >> 24) == r) {
                        unsigned int u = hw[(size_t)(p & 0xFFFFFFu) * 64 + lane];
                        ax += __uint_as_float(u << 16);
                        ay += __uint_as_float(u & 0xffff0000u);
                    }
                }
            }
            float sc = 1.0f / (float)outdeg[node];
            float2 o;
            o.x = ax * sc + bb.x;
            o.y = ay * sc + bb.y;
            reinterpret_cast<float2*>(out + (size_t)node * D)[lane] = o;
        }
    }
}

// ---------------------------------------------------------------------------
// Tier-3 fallback: atomic scatter path (shape-independent)
// ---------------------------------------------------------------------------
__global__ void deg_kernel(const int* __restrict__ src, int* __restrict__ deg, int E) {
    int i = blockIdx.x * blockDim.x + threadIdx.x;
    int stride = gridDim.x * blockDim.x;
    for (; i < E; i += stride) atomicAdd(&deg[src[i]], 1);
}

__global__ void scatter_kernel(const float* __restrict__ h,
                               const int* __restrict__ src,
                               const int* __restrict__ dst,
                               float* __restrict__ agg, int E) {
    int wave   = (int)((blockIdx.x * blockDim.x + threadIdx.x) >> 6);
    int lane   = threadIdx.x & 63;
    int nwaves = (int)((gridDim.x * blockDim.x) >> 6);
    for (int e = wave; e < E; e += nwaves) {
        int s = src[e];
        int d = dst[e];
        const float2 v = reinterpret_cast<const float2*>(h + (size_t)s * D)[lane];
        float* arow = agg + (size_t)d * D + lane * 2;
        atomicAdd(arow + 0, v.x);
        atomicAdd(arow + 1, v.y);
    }
}

__global__ __launch_bounds__(256) void gemm_finish(float* __restrict__ out,
                                                   const float* __restrict__ Wm,
                                                   const float* __restrict__ bias,
                                                   const int* __restrict__ deg,
                                                   int N) {
    __shared__ __align__(16) float tile[64][D];
    const int r0 = blockIdx.x * 64;
    const int t  = threadIdx.x;

    #pragma unroll
    for (int i = 0; i < 8; ++i) {
        int flat4 = i * 256 + t;
        int r     = flat4 >> 5;
        int c4    = flat4 & 31;
        int gr    = r0 + r;
        float4 v  = make_float4(0.f, 0.f, 0.f, 0.f);
        if (gr < N) v = reinterpret_cast<const float4*>(out + (size_t)gr * D)[c4];
        reinterpret_cast<float4*>(&tile[r][c4 * 4])[0] = v;
    }
    __syncthreads();

    const int wsel = t >> 6;
    const int j0   = (t & 63) * 2;

    float acc[16][2];
    #pragma unroll
    for (int r = 0; r < 16; ++r) { acc[r][0] = 0.f; acc[r][1] = 0.f; }

    for (int k = 0; k < D; k += 4) {
        float2 w[4];
        #pragma unroll
        for (int kk = 0; kk < 4; ++kk)
            w[kk] = reinterpret_cast<const float2*>(Wm + (size_t)(k + kk) * D + j0)[0];
        #pragma unroll
        for (int r = 0; r < 16; ++r) {
            float4 a = reinterpret_cast<const float4*>(&tile[wsel * 16 + r][k])[0];
            acc[r][0] += a.x * w[0].x + a.y * w[1].x + a.z * w[2].x + a.w * w[3].x;
            acc[r][1] += a.x * w[0].y + a.y * w[1].y + a.z * w[2].y + a.w * w[3].y;
        }
    }

    const float2 bb = reinterpret_cast<const float2*>(bias + j0)[0];
    #pragma unroll
    for (int r = 0; r < 16; ++r) {
        int gr = r0 + wsel * 16 + r;
        if (gr < N) {
            float sc = 1.0f / (float)deg[gr];
            float2 o;
            o.x = acc[r][0] * sc + bb.x;
            o.y = acc[r][1] * sc + bb.y;
            reinterpret_cast<float2*>(out + (size_t)gr * D + j0)[0] = o;
        }
    }
}

// ---------------------------------------------------------------------------
extern "C" void kernel_launch(void* const* d_in, const int* in_sizes, int n_in,
                              void* d_out, int out_size, void* d_ws, size_t ws_size,
                              hipStream_t stream) {
    const float* h   = (const float*)d_in[0];
    const float* Wm  = (const float*)d_in[1];
    const float* bia = (const float*)d_in[2];
    const int*   src = (const int*)d_in[3];
    const int*   dst = (const int*)d_in[4];
    float*       out = (float*)d_out;

    const int N = in_sizes[0] / D;   // 100000
    const int E = in_sizes[3];       // 1700000

    const int nb      = (N + BUCKET - 1) >> BSH;
    const int nchunk  = (E + CHUNK - 1) / CHUNK;
    const int gblocks = (N + 63) / 64;

    // ws (ints): outdeg[N] | Wtb[16384 shorts = 8192 ints] | cnt[nchunk*nb] |
    //            loff[nchunk*nb] | pairs[nchunk*CHUNK] | hw[N*64]
    size_t tier1_ints = (size_t)N + 8192 + (size_t)2 * nchunk * nb
                      + (size_t)nchunk * CHUNK + (size_t)N * 64;

    bool shape_ok = (N < (1 << 24)) && nb <= NB_MAX && nchunk <= NCHUNK_MAX;

    if (shape_ok && ws_size >= tier1_ints * sizeof(int)) {
        int* outdeg = (int*)d_ws;
        unsigned short* Wtb = (unsigned short*)(outdeg + N);
        int* cnt_g  = (int*)Wtb + 8192;   // 8192 ints = 16384 shorts past Wtb
        int* loff_g = cnt_g + (size_t)nchunk * nb;
        unsigned int* pairs = (unsigned int*)(loff_g + (size_t)nchunk * nb);
        unsigned int* hw = pairs + (size_t)nchunk * CHUNK;

        hipMemsetAsync(outdeg, 0, (size_t)N * sizeof(int), stream);

        conv_w<<<64, 256, 0, stream>>>(Wm, Wtb);

        phase1<<<nchunk + DEGB + gblocks, 256, 0, stream>>>(h, Wtb, src, dst, pairs,
                                                            cnt_g, loff_g, outdeg,
                                                            hw, E, nb, nchunk, N);

        sort_agg<<<nb, 512, 0, stream>>>(pairs, cnt_g, loff_g, hw,
                                         outdeg, bia, out, nb, nchunk, N);
    } else {
        // fallback: atomic scatter path
        int* deg = (int*)d_ws;
        hipMemsetAsync(out, 0, (size_t)out_size * sizeof(float), stream);
        hipMemsetAsync(deg, 0, (size_t)N * sizeof(int), stream);
        deg_kernel<<<2048, 256, 0, stream>>>(src, deg, E);
        scatter_kernel<<<8192, 256, 0, stream>>>(h, src, dst, out, E);
        gemm_finish<<<(N + 63) / 64, 256, 0, stream>>>(out, Wm, bia, deg, N);
    }
}

// Round 28
// 177.284 us; speedup vs baseline: 1.1055x; 1.0209x over previous
//
#include <hip/hip_runtime.h>

#define D 128           // feature dim
#define CHUNK 8192      // edges per partition block
#define NCHUNK_MAX 256  // supports E <= 2M
#define BSH 7           // bucket shift: bucket = 128 nodes
#define BUCKET 128
#define NB_MAX 1024     // supports N <= 131072
#define STAGE_CAP 3072  // sort_agg LDS stage entries (max random bucket ~2.4K)
#define DEGB 256        // out-degree histogram role blocks

typedef __attribute__((ext_vector_type(8))) short bf16x8;
typedef __attribute__((ext_vector_type(4))) float f32x4;

// ---------------------------------------------------------------------------
// bf16 pack (RNE; low 16 bits = FIRST element)
// ---------------------------------------------------------------------------
__device__ __forceinline__ unsigned int pack_bf16(float a, float b) {
    unsigned int ua = __float_as_uint(a), ub = __float_as_uint(b);
    ua = (ua + 0x7fffu + ((ua >> 16) & 1u)) >> 16;
    ub = (ub + 0x7fffu + ((ub >> 16) & 1u)) >> 16;
    return (ub << 16) | (ua & 0xffffu);
}

// inclusive wave-scan (64 lanes) of v; returns inclusive prefix for this lane
__device__ __forceinline__ int wave_iscan(int v, int lane) {
    #pragma unroll
    for (int off = 1; off < 64; off <<= 1) {
        int x = __shfl_up(v, off);
        if (lane >= off) v += x;
    }
    return v;
}

// ---------------------------------------------------------------------------
// conv_w: Wt_bf16[col][k] = bf16(W[k][col])  (128x128 = 16384 shorts = 32 KB)
// ---------------------------------------------------------------------------
__global__ __launch_bounds__(256) void conv_w(const float* __restrict__ W,
                                              unsigned short* __restrict__ Wtb) {
    int i = blockIdx.x * 256 + threadIdx.x;   // 16384 total
    int col = i >> 7, k = i & 127;
    unsigned int u = __float_as_uint(W[k * D + col]);
    u = (u + 0x7fffu + ((u >> 16) & 1u)) >> 16;
    Wtb[i] = (unsigned short)u;
}

// ---------------------------------------------------------------------------
// Phase 1 (fused, 256-thread blocks, 3 roles):
//  [0, nchunk)            partition 8192 edges by 128-node dst bucket
//                         (passes 1&2 int4: 4 loads in flight per lane —
//                         latency-bound regime, VALU idle post-MFMA)
//  [nchunk, nchunk+DEGB)  out-degree histogram (grid-stride, scalar)
//  [nchunk+DEGB, ...)     hw = bf16(h @ W) via MFMA 16x16x32, 64-row tile
// ---------------------------------------------------------------------------
struct Phase1Smem {
    struct {
        int hist[NB_MAX];            // counts -> offsets -> cursors
        unsigned int stage[CHUNK];
    } p;                              // 36 KB (partition role only)
};

__global__ __launch_bounds__(256) void phase1(const float* __restrict__ h,
                                              const unsigned short* __restrict__ Wtb,
                                              const int* __restrict__ src,
                                              const int* __restrict__ dst,
                                              unsigned int* __restrict__ pairs,
                                              int* __restrict__ cnt_g,
                                              int* __restrict__ loff_g,
                                              int* __restrict__ outdeg,
                                              unsigned int* __restrict__ hw,
                                              int E, int nb, int nchunk, int N) {
    __shared__ Phase1Smem sm;
    __shared__ int redw[4];
    const int t   = threadIdx.x;
    const int bid = (int)blockIdx.x;

    if (bid < nchunk) {
        // ---------------- partition role (priority-boosted) ----------------
        __builtin_amdgcn_s_setprio(1);
        const int c  = bid;
        const int e0 = c * CHUNK;
        const int n  = min(CHUNK, E - e0);
        const int n4 = n >> 2;

        for (int i = t; i < nb; i += 256) sm.p.hist[i] = 0;
        __syncthreads();

        // pass 1: bucket histogram (int4: 4 loads in flight)
        {
            const int4* dst4 = reinterpret_cast<const int4*>(dst + e0);
            for (int i = t; i < n4; i += 256) {
                int4 d4 = dst4[i];
                atomicAdd(&sm.p.hist[d4.x >> BSH], 1);
                atomicAdd(&sm.p.hist[d4.y >> BSH], 1);
                atomicAdd(&sm.p.hist[d4.z >> BSH], 1);
                atomicAdd(&sm.p.hist[d4.w >> BSH], 1);
            }
            for (int i = (n4 << 2) + t; i < n; i += 256)
                atomicAdd(&sm.p.hist[dst[e0 + i] >> BSH], 1);
        }
        __syncthreads();

        // export counts
        for (int i = t; i < nb; i += 256) cnt_g[(size_t)c * nb + i] = sm.p.hist[i];
        __syncthreads();

        // PARALLEL exclusive scan of hist[0..nb) in place (4 elems/thread)
        {
            const int lane = t & 63;
            const int w    = t >> 6;
            const int i0   = t * 4;
            int v0 = (i0 + 0 < nb) ? sm.p.hist[i0 + 0] : 0;
            int v1 = (i0 + 1 < nb) ? sm.p.hist[i0 + 1] : 0;
            int v2 = (i0 + 2 < nb) ? sm.p.hist[i0 + 2] : 0;
            int v3 = (i0 + 3 < nb) ? sm.p.hist[i0 + 3] : 0;
            int s   = v0 + v1 + v2 + v3;
            int inc = wave_iscan(s, lane);
            if (lane == 63) redw[w] = inc;
            __syncthreads();
            int wpre = 0;
            #pragma unroll
            for (int q = 0; q < 4; ++q) wpre += (q < w) ? redw[q] : 0;
            int excl = wpre + inc - s;
            if (i0 + 0 < nb) sm.p.hist[i0 + 0] = excl;  excl += v0;
            if (i0 + 1 < nb) sm.p.hist[i0 + 1] = excl;  excl += v1;
            if (i0 + 2 < nb) sm.p.hist[i0 + 2] = excl;  excl += v2;
            if (i0 + 3 < nb) sm.p.hist[i0 + 3] = excl;
        }
        __syncthreads();

        // export offsets (hist now doubles as the pass-2 cursor array)
        for (int i = t; i < nb; i += 256) loff_g[(size_t)c * nb + i] = sm.p.hist[i];
        __syncthreads();

        // pass 2: scatter into LDS stage (int4: 8 loads in flight)
        {
            const int4* dst4 = reinterpret_cast<const int4*>(dst + e0);
            const int4* src4 = reinterpret_cast<const int4*>(src + e0);
            for (int i = t; i < n4; i += 256) {
                int4 d4 = dst4[i];
                int4 s4 = src4[i];
                int sl0 = atomicAdd(&sm.p.hist[d4.x >> BSH], 1);
                int sl1 = atomicAdd(&sm.p.hist[d4.y >> BSH], 1);
                int sl2 = atomicAdd(&sm.p.hist[d4.z >> BSH], 1);
                int sl3 = atomicAdd(&sm.p.hist[d4.w >> BSH], 1);
                sm.p.stage[sl0] = ((unsigned int)(d4.x & (BUCKET - 1)) << 24) | (unsigned int)s4.x;
                sm.p.stage[sl1] = ((unsigned int)(d4.y & (BUCKET - 1)) << 24) | (unsigned int)s4.y;
                sm.p.stage[sl2] = ((unsigned int)(d4.z & (BUCKET - 1)) << 24) | (unsigned int)s4.z;
                sm.p.stage[sl3] = ((unsigned int)(d4.w & (BUCKET - 1)) << 24) | (unsigned int)s4.w;
            }
            for (int i = (n4 << 2) + t; i < n; i += 256) {
                int d = dst[e0 + i];
                int s = src[e0 + i];
                int slot = atomicAdd(&sm.p.hist[d >> BSH], 1);
                sm.p.stage[slot] = ((unsigned int)(d & (BUCKET - 1)) << 24) | (unsigned int)s;
            }
        }
        __syncthreads();

        // pass 3: dense streamout (scalar, as r24)
        for (int i = t; i < n; i += 256) pairs[e0 + i] = sm.p.stage[i];
        __builtin_amdgcn_s_setprio(0);
    } else if (bid < nchunk + DEGB) {
        // ---------------- out-degree role (grid-stride on idle CUs) --------
        int i = (bid - nchunk) * 256 + t;
        const int stride = DEGB * 256;
        for (; i < E; i += stride) atomicAdd(&outdeg[src[i]], 1);
    } else {
        // ---------------- GEMM role (MFMA, 64-row tile, no LDS) ------------
        const int r0 = (bid - nchunk - DEGB) * 64;
        const int w  = t >> 6;          // wave 0..3 -> rows w*16..w*16+15
        const int l  = t & 63;
        const int hr = l & 15;          // lane's h-row within the 16
        const int cg = l >> 4;          // k-group / col-group (0..3)

        const int gr  = r0 + w * 16 + hr;
        const int grc = (gr < N) ? gr : (N - 1);   // clamp for safe loads

        f32x4 acc[8];
        #pragma unroll
        for (int ct = 0; ct < 8; ++ct) acc[ct] = (f32x4){0.f, 0.f, 0.f, 0.f};

        #pragma unroll
        for (int kg = 0; kg < 4; ++kg) {
            const float* hp = h + (size_t)grc * D + kg * 32 + cg * 8;
            float4 h0 = reinterpret_cast<const float4*>(hp)[0];
            float4 h1 = reinterpret_cast<const float4*>(hp)[1];
            unsigned int hu[4] = { pack_bf16(h0.x, h0.y), pack_bf16(h0.z, h0.w),
                                   pack_bf16(h1.x, h1.y), pack_bf16(h1.z, h1.w) };
            bf16x8 hf = *reinterpret_cast<bf16x8*>(hu);

            #pragma unroll
            for (int ct = 0; ct < 8; ++ct) {
                bf16x8 wf = *reinterpret_cast<const bf16x8*>(
                    Wtb + ((size_t)(ct * 16 + hr) * D + kg * 32 + cg * 8));
                acc[ct] = __builtin_amdgcn_mfma_f32_16x16x32_bf16(wf, hf, acc[ct], 0, 0, 0);
            }
        }

        if (gr < N) {
            #pragma unroll
            for (int ct = 0; ct < 8; ++ct) {
                int cpb = ct * 8 + cg * 2;
                hw[(size_t)gr * 64 + cpb]     = pack_bf16(acc[ct][0], acc[ct][1]);
                hw[(size_t)gr * 64 + cpb + 1] = pack_bf16(acc[ct][2], acc[ct][3]);
            }
        }
    }
}

// ---------------------------------------------------------------------------
// sort_agg: fused {per-bucket counting sort -> LDS} + {gather hw rows, fused
// deg/bias epilogue}. One 512-thread block (8 waves) per 128-node bucket.
// (r24/r27 version, byte-identical)
// ---------------------------------------------------------------------------
__global__ __launch_bounds__(512) void sort_agg(const unsigned int* __restrict__ pairs,
                                                const int* __restrict__ cnt_g,
                                                const int* __restrict__ loff_g,
                                                const unsigned int* __restrict__ hw,
                                                const int* __restrict__ outdeg,
                                                const float* __restrict__ bias,
                                                float* __restrict__ out,
                                                int nb, int nchunk, int N) {
    __shared__ int sec_base[NCHUNK_MAX + 1];
    __shared__ int sec_lo[NCHUNK_MAX];
    __shared__ int dstart[BUCKET + 1];
    __shared__ int dcur[BUCKET];
    __shared__ int redw[8];
    __shared__ unsigned int stage[STAGE_CAP];

    const int t    = threadIdx.x;
    const int b    = blockIdx.x;
    const int lane = t & 63;
    const int w    = t >> 6;

    for (int c = t; c < nchunk; c += 512) {
        sec_base[c] = cnt_g[(size_t)c * nb + b];
        sec_lo[c]   = loff_g[(size_t)c * nb + b];
    }
    if (t < BUCKET) dstart[t] = 0;
    __syncthreads();

    // PARALLEL exclusive scan of sec_base[0..nchunk) (1 elem/thread)
    {
        int v   = (t < nchunk) ? sec_base[t] : 0;
        int inc = wave_iscan(v, lane);
        if (lane == 63) redw[w] = inc;
        __syncthreads();
        int wpre = 0;
        #pragma unroll
        for (int q = 0; q < 8; ++q) wpre += (q < w) ? redw[q] : 0;
        int excl = wpre + inc - v;
        __syncthreads();
        if (t < nchunk) sec_base[t] = excl;
        if (t == nchunk - 1) sec_base[nchunk] = excl + v;
    }
    __syncthreads();

    const int total = sec_base[nchunk];

    // pass 1: local-dst histogram (binary search section)
    for (int j = t; j < total; j += 512) {
        int lo = 0, hi = nchunk - 1;
        while (lo < hi) { int mid = (lo + hi + 1) >> 1; if (sec_base[mid] <= j) lo = mid; else hi = mid - 1; }
        unsigned int p = pairs[(size_t)lo * CHUNK + sec_lo[lo] + (j - sec_base[lo])];
        atomicAdd(&dstart[p >> 24], 1);
    }
    __syncthreads();

    // PARALLEL exclusive scan of dstart[0..BUCKET)
    {
        int v   = (t < BUCKET) ? dstart[t] : 0;
        int inc = wave_iscan(v, lane);
        if (lane == 63) redw[w] = inc;
        __syncthreads();
        int wpre = 0;
        #pragma unroll
        for (int q = 0; q < 8; ++q) wpre += (q < w) ? redw[q] : 0;
        int excl = wpre + inc - v;
        __syncthreads();
        if (t < BUCKET) { dstart[t] = excl; dcur[t] = excl; }
        if (t == BUCKET - 1) dstart[BUCKET] = excl + v;
    }
    __syncthreads();

    const float2 bb = reinterpret_cast<const float2*>(bias)[lane];

    if (total <= STAGE_CAP) {
        // pass 2: scatter src into LDS stage ordered by local dst
        for (int j = t; j < total; j += 512) {
            int lo = 0, hi = nchunk - 1;
            while (lo < hi) { int mid = (lo + hi + 1) >> 1; if (sec_base[mid] <= j) lo = mid; else hi = mid - 1; }
            unsigned int p = pairs[(size_t)lo * CHUNK + sec_lo[lo] + (j - sec_base[lo])];
            int slot = atomicAdd(&dcur[p >> 24], 1);
            stage[slot] = p & 0xFFFFFFu;
        }
        __syncthreads();

        // gather + epilogue: wave per local node, round-robin, ILP-8
        for (int r = w; r < BUCKET; r += 8) {
            const int node = (b << BSH) + r;
            if (node >= N) break;
            const int e0 = dstart[r], e1 = dstart[r + 1];
            float ax = 0.f, ay = 0.f;
            int e = e0;
            for (; e + 8 <= e1; e += 8) {
                int sx[8];
                #pragma unroll
                for (int q = 0; q < 8; ++q) sx[q] = (int)stage[e + q];
                unsigned int u[8];
                #pragma unroll
                for (int q = 0; q < 8; ++q) u[q] = hw[(size_t)sx[q] * 64 + lane];
                #pragma unroll
                for (int q = 0; q < 8; ++q) {
                    ax += __uint_as_float(u[q] << 16);
                    ay += __uint_as_float(u[q] & 0xffff0000u);
                }
            }
            for (; e + 4 <= e1; e += 4) {
                int s0 = (int)stage[e],     s1 = (int)stage[e + 1];
                int s2 = (int)stage[e + 2], s3 = (int)stage[e + 3];
                unsigned int u0 = hw[(size_t)s0 * 64 + lane];
                unsigned int u1 = hw[(size_t)s1 * 64 + lane];
                unsigned int u2 = hw[(size_t)s2 * 64 + lane];
                unsigned int u3 = hw[(size_t)s3 * 64 + lane];
                ax += __uint_as_float(u0 << 16) + __uint_as_float(u1 << 16)
                    + __uint_as_float(u2 << 16) + __uint_as_float(u3 << 16);
                ay += __uint_as_float(u0 & 0xffff0000u) + __uint_as_float(u1 & 0xffff0000u)
                    + __uint_as_float(u2 & 0xffff0000u) + __uint_as_float(u3 & 0xffff0000u);
            }
            for (; e < e1; ++e) {
                unsigned int u = hw[(size_t)stage[e] * 64 + lane];
                ax += __uint_as_float(u << 16);
                ay += __uint_as_float(u & 0xffff0000u);
            }
            float sc = 1.0f / (float)outdeg[node];
            float2 o;
            o.x = ax * sc + bb.x;
            o.y = ay * sc + bb.y;
            reinterpret_cast<float2*>(out + (size_t)node * D)[lane] = o;
        }
    } else {
        // slow path (pathological skew only): wave per node, full bucket scan
        for (int r = w; r < BUCKET; r += 8) {
            const int node = (b << BSH) + r;
            if (node >= N) break;
            float ax = 0.f, ay = 0.f;
            for (int c = 0; c < nchunk; ++c) {
                const int cb = sec_base[c], ce = sec_base[c + 1];
                const size_t pb = (size_t)c * CHUNK + sec_lo[c];
                for (int j = cb; j < ce; ++j) {
                    unsigned int p = pairs[pb + (j - cb)];
                    if ((int)(p >> 24) == r) {
                        unsigned int u = hw[(size_t)(p & 0xFFFFFFu) * 64 + lane];
                        ax += __uint_as_float(u << 16);
                        ay += __uint_as_float(u & 0xffff0000u);
                    }
                }
            }
            float sc = 1.0f / (float)outdeg[node];
            float2 o;
            o.x = ax * sc + bb.x;
            o.y = ay * sc + bb.y;
            reinterpret_cast<float2*>(out + (size_t)node * D)[lane] = o;
        }
    }
}

// ---------------------------------------------------------------------------
// Tier-3 fallback: atomic scatter path (shape-independent)
// ---------------------------------------------------------------------------
__global__ void deg_kernel(const int* __restrict__ src, int* __restrict__ deg, int E) {
    int i = blockIdx.x * blockDim.x + threadIdx.x;
    int stride = gridDim.x * blockDim.x;
    for (; i < E; i += stride) atomicAdd(&deg[src[i]], 1);
}

__global__ void scatter_kernel(const float* __restrict__ h,
                               const int* __restrict__ src,
                               const int* __restrict__ dst,
                               float* __restrict__ agg, int E) {
    int wave   = (int)((blockIdx.x * blockDim.x + threadIdx.x) >> 6);
    int lane   = threadIdx.x & 63;
    int nwaves = (int)((gridDim.x * blockDim.x) >> 6);
    for (int e = wave; e < E; e += nwaves) {
        int s = src[e];
        int d = dst[e];
        const float2 v = reinterpret_cast<const float2*>(h + (size_t)s * D)[lane];
        float* arow = agg + (size_t)d * D + lane * 2;
        atomicAdd(arow + 0, v.x);
        atomicAdd(arow + 1, v.y);
    }
}

__global__ __launch_bounds__(256) void gemm_finish(float* __restrict__ out,
                                                   const float* __restrict__ Wm,
                                                   const float* __restrict__ bias,
                                                   const int* __restrict__ deg,
                                                   int N) {
    __shared__ __align__(16) float tile[64][D];
    const int r0 = blockIdx.x * 64;
    const int t  = threadIdx.x;

    #pragma unroll
    for (int i = 0; i < 8; ++i) {
        int flat4 = i * 256 + t;
        int r     = flat4 >> 5;
        int c4    = flat4 & 31;
        int gr    = r0 + r;
        float4 v  = make_float4(0.f, 0.f, 0.f, 0.f);
        if (gr < N) v = reinterpret_cast<const float4*>(out + (size_t)gr * D)[c4];
        reinterpret_cast<float4*>(&tile[r][c4 * 4])[0] = v;
    }
    __syncthreads();

    const int wsel = t >> 6;
    const int j0   = (t & 63) * 2;

    float acc[16][2];
    #pragma unroll
    for (int r = 0; r < 16; ++r) { acc[r][0] = 0.f; acc[r][1] = 0.f; }

    for (int k = 0; k < D; k += 4) {
        float2 w[4];
        #pragma unroll
        for (int kk = 0; kk < 4; ++kk)
            w[kk] = reinterpret_cast<const float2*>(Wm + (size_t)(k + kk) * D + j0)[0];
        #pragma unroll
        for (int r = 0; r < 16; ++r) {
            float4 a = reinterpret_cast<const float4*>(&tile[wsel * 16 + r][k])[0];
            acc[r][0] += a.x * w[0].x + a.y * w[1].x + a.z * w[2].x + a.w * w[3].x;
            acc[r][1] += a.x * w[0].y + a.y * w[1].y + a.z * w[2].y + a.w * w[3].y;
        }
    }

    const float2 bb = reinterpret_cast<const float2*>(bias + j0)[0];
    #pragma unroll
    for (int r = 0; r < 16; ++r) {
        int gr = r0 + wsel * 16 + r;
        if (gr < N) {
            float sc = 1.0f / (float)deg[gr];
            float2 o;
            o.x = acc[r][0] * sc + bb.x;
            o.y = acc[r][1] * sc + bb.y;
            reinterpret_cast<float2*>(out + (size_t)gr * D + j0)[0] = o;
        }
    }
}

// ---------------------------------------------------------------------------
extern "C" void kernel_launch(void* const* d_in, const int* in_sizes, int n_in,
                              void* d_out, int out_size, void* d_ws, size_t ws_size,
                              hipStream_t stream) {
    const float* h   = (const float*)d_in[0];
    const float* Wm  = (const float*)d_in[1];
    const float* bia = (const float*)d_in[2];
    const int*   src = (const int*)d_in[3];
    const int*   dst = (const int*)d_in[4];
    float*       out = (float*)d_out;

    const int N = in_sizes[0] / D;   // 100000
    const int E = in_sizes[3];       // 1700000

    const int nb      = (N + BUCKET - 1) >> BSH;
    const int nchunk  = (E + CHUNK - 1) / CHUNK;
    const int gblocks = (N + 63) / 64;

    // ws (ints): outdeg[N] | Wtb[16384 shorts = 8192 ints] | cnt[nchunk*nb] |
    //            loff[nchunk*nb] | pairs[nchunk*CHUNK] | hw[N*64]
    size_t tier1_ints = (size_t)N + 8192 + (size_t)2 * nchunk * nb
                      + (size_t)nchunk * CHUNK + (size_t)N * 64;

    bool shape_ok = (N < (1 << 24)) && nb <= NB_MAX && nchunk <= NCHUNK_MAX;

    if (shape_ok && ws_size >= tier1_ints * sizeof(int)) {
        int* outdeg = (int*)d_ws;
        unsigned short* Wtb = (unsigned short*)(outdeg + N);
        int* cnt_g  = (int*)Wtb + 8192;   // 8192 ints = 16384 shorts past Wtb
        int* loff_g = cnt_g + (size_t)nchunk * nb;
        unsigned int* pairs = (unsigned int*)(loff_g + (size_t)nchunk * nb);
        unsigned int* hw = pairs + (size_t)nchunk * CHUNK;

        hipMemsetAsync(outdeg, 0, (size_t)N * sizeof(int), stream);

        conv_w<<<64, 256, 0, stream>>>(Wm, Wtb);

        phase1<<<nchunk + DEGB + gblocks, 256, 0, stream>>>(h, Wtb, src, dst, pairs,
                                                            cnt_g, loff_g, outdeg,
                                                            hw, E, nb, nchunk, N);

        sort_agg<<<nb, 512, 0, stream>>>(pairs, cnt_g, loff_g, hw,
                                         outdeg, bia, out, nb, nchunk, N);
    } else {
        // fallback: atomic scatter path
        int* deg = (int*)d_ws;
        hipMemsetAsync(out, 0, (size_t)out_size * sizeof(float), stream);
        hipMemsetAsync(deg, 0, (size_t)N * sizeof(int), stream);
        deg_kernel<<<2048, 256, 0, stream>>>(src, deg, E);
        scatter_kernel<<<8192, 256, 0, stream>>>(h, src, dst, out, E);
        gemm_finish<<<(N + 63) / 64, 256, 0, stream>>>(out, Wm, bia, deg, N);
    }
}